// Round 6
// baseline (17686.343 us; speedup 1.0000x reference)
//
#include <hip/hip_runtime.h>
#include <cstdint>
#include <cstddef>

#define Bz 64
#define Tz 512
#define Iz 512
#define Hz 512
#define Cz 4096
#define NWG 256

typedef __attribute__((ext_vector_type(8))) short short8;
typedef __attribute__((ext_vector_type(4))) float floatx4;
typedef __attribute__((ext_vector_type(2))) float floatx2;
typedef unsigned long long u64;
typedef unsigned int u32;

union U16S8 { u64 u[2]; short8 s; };

__device__ __forceinline__ unsigned short f2bf(float f) {
  union { float f; unsigned u; } v; v.f = f;
  unsigned r = v.u + 0x7fffu + ((v.u >> 16) & 1u);
  return (unsigned short)(r >> 16);
}
__device__ __forceinline__ float bf2f(unsigned short h) {
  union { unsigned u; float f; } v; v.u = ((unsigned)h) << 16; return v.f;
}
__device__ __forceinline__ float sigmoidf_(float x) { return 1.0f / (1.0f + __expf(-x)); }
// tanh = 1 - 2/(e^{2x}+1): no NaN for any x (denominator >= 1), saturates correctly
__device__ __forceinline__ float tanhf_(float x) { return 1.0f - 2.0f / (__expf(2.0f * x) + 1.0f); }

// coherent 16-B read = two relaxed agent-scope u64 loads (sc1: bypass stale L1/L2)
__device__ __forceinline__ short8 ald16(const void* p) {
  u64* q = (u64*)p;
  U16S8 t;
  t.u[0] = __hip_atomic_load(q,     __ATOMIC_RELAXED, __HIP_MEMORY_SCOPE_AGENT);
  t.u[1] = __hip_atomic_load(q + 1, __ATOMIC_RELAXED, __HIP_MEMORY_SCOPE_AGENT);
  return t.s;
}

// ---------------- precast kernels (packed path) ----------------

// [Wi;Ws] -> B-fragment order: id = (((w*4 + nt)*32 + kt)*64 + lane)
__global__ __launch_bounds__(256) void precast_wpk(const float* __restrict__ Wi,
                                                   const float* __restrict__ Wst,
                                                   short* __restrict__ wpk) {
  int id = blockIdx.x * 256 + threadIdx.x;       // 0..2097151
  int l  = id & 63;
  int kt = (id >> 6) & 31;
  int nt = (id >> 11) & 3;
  int w  = id >> 13;
  int r  = nt * Cz + w * 16 + (l & 15);
  int k  = kt * 32 + (l >> 4) * 8;
  const float* p = (k < Iz) ? (Wi + (size_t)r * Iz + k)
                            : (Wst + (size_t)r * Hz + (k - Iz));
  short8 v;
  #pragma unroll
  for (int i = 0; i < 8; ++i) v[i] = (short)f2bf(p[i]);
  *(short8*)(wpk + (size_t)id * 8) = v;
}

// Wp^T full-K fragment order: id = ((jg*128 + kt)*64 + lane); j=jg*16+(l&15), c=kt*32+(l>>4)*8
__global__ __launch_bounds__(256) void precast_wpp(const float* __restrict__ Wp,
                                                   short* __restrict__ wpp) {
  int id = blockIdx.x * 256 + threadIdx.x;       // 0..262143
  int l  = id & 63;
  int kt = (id >> 6) & 127;
  int jg = id >> 13;
  int j  = jg * 16 + (l & 15);
  int c  = kt * 32 + (l >> 4) * 8;
  const float* p = Wp + (size_t)j * Cz + c;
  short8 v;
  #pragma unroll
  for (int i = 0; i < 8; ++i) v[i] = (short)f2bf(p[i]);
  *(short8*)(wpp + (size_t)id * 8) = v;
}

__global__ __launch_bounds__(256) void precast_x(const float* __restrict__ x,
                                                 unsigned short* __restrict__ xb) {
  size_t id = ((size_t)blockIdx.x * 256 + threadIdx.x) * 4;
  float4 v = *(const float4*)(x + id);
  ushort4 o;
  o.x = f2bf(v.x); o.y = f2bf(v.y); o.z = f2bf(v.z); o.w = f2bf(v.w);
  *(ushort4*)(xb + id) = o;
}

// ---------------- persistent kernel: 256 WGs x 512 thr ----------------
// All WGs: gates for cells [w*16, w*16+16).
// WGs with (w&3)==0 additionally run proj tile p=w>>2: jg=p&31 (16 j), bg=p>>5 (32 b), K=4096.
// Sync chain per step: hfl -> gates-h -> abuf -> afl -> proj -> h -> hfl. No split-K partials.
template <bool PK>
__global__ __launch_bounds__(512, 2)
void lstm_persist(const float* __restrict__ xf, const unsigned short* __restrict__ xb,
                  const float* __restrict__ Wi, const float* __restrict__ Wst,
                  const float* __restrict__ Wp,
                  const short* __restrict__ wpk, const short* __restrict__ wpp,
                  const float* __restrict__ bstate, const int* __restrict__ lens,
                  unsigned short* __restrict__ Hbuf,   // 2 parity x [64][512] bf16
                  int* __restrict__ afl,               // [256] stride 16 ints
                  int* __restrict__ hfl,               // [64]  stride 16 ints
                  unsigned short* __restrict__ abuf,   // 2 parity x [64][4096] bf16
                  float* __restrict__ outp, float* __restrict__ final_h,
                  float* __restrict__ final_c) {
  __shared__ float glds[64 * 64];          // 16 KB gate-tile spill (XOR-swizzled cols)
  __shared__ float pld[8 * 2 * 16 * 16];   // 16 KB proj split-K partials

  const int tid  = threadIdx.x;
  const int w    = blockIdx.x;
  const int lane = tid & 63;
  const int wv   = tid >> 6;        // 0..7
  const int lrow = lane & 15;
  const int lq   = lane >> 4;
  const int bt   = wv >> 1;         // gates batch 16-tile (A row base bt*16+lrow)
  const int ntb  = (wv & 1) * 2;    // gates gate-pair base {0,2}

  // ---- gates epilogue ownership: thread -> (batch b_e, cells cc2, cc2+1) ----
  const int b_e  = tid >> 3;
  const int cc2  = (tid & 7) * 2;
  const int cell2 = w * 16 + cc2;
  float bsv[4][2];
  #pragma unroll
  for (int g = 0; g < 4; ++g) {
    bsv[g][0] = bstate[g * Cz + cell2];
    bsv[g][1] = bstate[g * Cz + cell2 + 1];
  }
  const int len_e = lens[b_e];
  float c_reg[2] = {0.f, 0.f};

  // ---- proj ownership ----
  const bool isProj = (w & 3) == 0;
  const int p  = w >> 2;
  const int jg = p & 31;
  const int bg = p >> 5;
  int b_p = 0, lenp = 0, jf2 = 0, mt_p = 0, row_p = 0;
  float h_old[2] = {0.f, 0.f};
  if (isProj && tid < 256) {
    mt_p  = tid >> 7;              // 0..1
    row_p = (tid >> 3) & 15;
    b_p   = bg * 32 + mt_p * 16 + row_p;
    jf2   = jg * 16 + (tid & 7) * 2;
    lenp  = lens[b_p];
  }

  for (int t = 0; t < Tz; ++t) {
    const unsigned short* Hread = Hbuf + (size_t)(t & 1) * Bz * Hz;
    unsigned short* Hwr         = Hbuf + (size_t)((t & 1) ^ 1) * Bz * Hz;
    unsigned short* abufT       = abuf + (size_t)(t & 1) * Bz * Cz;

    // =================== gates: x half (kt 0..15) — no h dependency ===================
    floatx4 acc0 = {0.f, 0.f, 0.f, 0.f};
    floatx4 acc1 = {0.f, 0.f, 0.f, 0.f};
    const int arow = bt * 16 + lrow;

    #pragma unroll 4
    for (int kt = 0; kt < 16; ++kt) {
      short8 afr;
      if (PK) {
        afr = *(const short8*)(xb + ((size_t)arow * Tz + t) * Iz + kt * 32 + lq * 8);
      } else {
        const float* pp = xf + ((size_t)arow * Tz + t) * Iz + kt * 32 + lq * 8;
        #pragma unroll
        for (int i = 0; i < 8; ++i) afr[i] = (short)f2bf(pp[i]);
      }
      short8 bfr0, bfr1;
      if (PK) {
        const short* bp = wpk + ((((size_t)w * 4 + ntb) * 32 + kt) * 64 + lane) * 8;
        bfr0 = *(const short8*)bp;
        bfr1 = *(const short8*)(bp + (size_t)32 * 64 * 8);
      } else {
        #pragma unroll
        for (int hh = 0; hh < 2; ++hh) {
          int r = (ntb + hh) * Cz + w * 16 + lrow;
          const float* pp = Wi + (size_t)r * Iz + kt * 32 + lq * 8;
          short8 v;
          #pragma unroll
          for (int i = 0; i < 8; ++i) v[i] = (short)f2bf(pp[i]);
          if (hh == 0) bfr0 = v; else bfr1 = v;
        }
      }
      acc0 = __builtin_amdgcn_mfma_f32_16x16x32_bf16(afr, bfr0, acc0, 0, 0, 0);
      acc1 = __builtin_amdgcn_mfma_f32_16x16x32_bf16(afr, bfr1, acc1, 0, 0, 0);
    }

    // ---- wait: h(t-1) complete (64 proj tiles) ----
    if (tid < 64) {
      while (__hip_atomic_load(&hfl[tid * 16], __ATOMIC_RELAXED,
                               __HIP_MEMORY_SCOPE_AGENT) < t)
        __builtin_amdgcn_s_sleep(1);
    }
    __syncthreads();
    __asm__ volatile("" ::: "memory");

    // =================== gates: h half (kt 16..31), direct sc1 A loads ==============
    #pragma unroll
    for (int blk = 0; blk < 2; ++blk) {
      short8 hf[8];
      #pragma unroll
      for (int i = 0; i < 8; ++i)
        hf[i] = ald16(Hread + arow * Hz + (blk * 8 + i) * 32 + lq * 8);
      #pragma unroll
      for (int i = 0; i < 8; ++i) {
        const int kt = 16 + blk * 8 + i;
        short8 bfr0, bfr1;
        if (PK) {
          const short* bp = wpk + ((((size_t)w * 4 + ntb) * 32 + kt) * 64 + lane) * 8;
          bfr0 = *(const short8*)bp;
          bfr1 = *(const short8*)(bp + (size_t)32 * 64 * 8);
        } else {
          #pragma unroll
          for (int hh = 0; hh < 2; ++hh) {
            int r = (ntb + hh) * Cz + w * 16 + lrow;
            const float* pp = Wst + (size_t)r * Hz + (kt - 16) * 32 + lq * 8;
            short8 v;
            #pragma unroll
            for (int ii = 0; ii < 8; ++ii) v[ii] = (short)f2bf(pp[ii]);
            if (hh == 0) bfr0 = v; else bfr1 = v;
          }
        }
        acc0 = __builtin_amdgcn_mfma_f32_16x16x32_bf16(hf[i], bfr0, acc0, 0, 0, 0);
        acc1 = __builtin_amdgcn_mfma_f32_16x16x32_bf16(hf[i], bfr1, acc1, 0, 0, 0);
      }
    }

    {  // spill gate tile to LDS; col n = gate*16 + cell, phys col = n ^ row
      const int sb0 = bt * 16 + lq * 4;
      const int n0  = ntb * 16 + lrow;
      #pragma unroll
      for (int r = 0; r < 4; ++r) {
        int row = sb0 + r;
        glds[row * 64 + ((n0 ^ row) & 63)]        = acc0[r];
        glds[row * 64 + (((n0 + 16) ^ row) & 63)] = acc1[r];
      }
    }
    __syncthreads();
    {  // fp32 epilogue: 2 cells/thread, c in regs, one packed sc1 store
      float a_out[2];
      #pragma unroll
      for (int e = 0; e < 2; ++e) {
        int cc = cc2 + e;
        float g0 = glds[b_e * 64 + (((0  + cc) ^ b_e) & 63)] + bsv[0][e];
        float g1 = glds[b_e * 64 + (((16 + cc) ^ b_e) & 63)] + bsv[1][e];
        float g2 = glds[b_e * 64 + (((32 + cc) ^ b_e) & 63)] + bsv[2][e];
        float g3 = glds[b_e * 64 + (((48 + cc) ^ b_e) & 63)] + bsv[3][e];
        float mem = sigmoidf_(g0) * tanhf_(g2) + sigmoidf_(g1) * c_reg[e];
        mem = fminf(fmaxf(mem, -3.f), 3.f);
        bool active = t < len_e;
        c_reg[e] = active ? mem : c_reg[e];
        a_out[e] = sigmoidf_(g3) * tanhf_(mem);
      }
      u32 pk2 = (u32)f2bf(a_out[0]) | ((u32)f2bf(a_out[1]) << 16);
      __hip_atomic_store((u32*)abufT + (((size_t)b_e * Cz + cell2) >> 1), pk2,
                         __ATOMIC_RELAXED, __HIP_MEMORY_SCOPE_AGENT);
      if (t == Tz - 1) {
        __builtin_nontemporal_store(c_reg[0], final_c + (size_t)b_e * Cz + cell2);
        __builtin_nontemporal_store(c_reg[1], final_c + (size_t)b_e * Cz + cell2 + 1);
      }
    }
    __syncthreads();            // drains every wave's vmcnt -> abuf at coherence point
    if (tid == 0) {
      __asm__ volatile("s_waitcnt vmcnt(0)" ::: "memory");
      __hip_atomic_store(&afl[w * 16], t + 1, __ATOMIC_RELAXED, __HIP_MEMORY_SCOPE_AGENT);
    }

    // =================== proj (64 WGs): full K=4096, intra-WG split-K ==============
    if (isProj) {
      if (tid < 256) {
        while (__hip_atomic_load(&afl[tid * 16], __ATOMIC_RELAXED,
                                 __HIP_MEMORY_SCOPE_AGENT) < t + 1)
          __builtin_amdgcn_s_sleep(1);
      }
      __syncthreads();
      __asm__ volatile("" ::: "memory");

      floatx4 pc0 = {0.f, 0.f, 0.f, 0.f};
      floatx4 pc1 = {0.f, 0.f, 0.f, 0.f};
      const int kb = wv * 512;            // this wave's K slice
      #pragma unroll
      for (int blk = 0; blk < 4; ++blk) {
        short8 af0[4], af1[4];
        #pragma unroll
        for (int i = 0; i < 4; ++i) {
          int k = kb + (blk * 4 + i) * 32 + lq * 8;
          af0[i] = ald16(abufT + (size_t)(bg * 32 + lrow) * Cz + k);
          af1[i] = ald16(abufT + (size_t)(bg * 32 + 16 + lrow) * Cz + k);
        }
        #pragma unroll
        for (int i = 0; i < 4; ++i) {
          int kt2 = blk * 4 + i;
          short8 bfr;
          if (PK) {
            bfr = *(const short8*)(wpp + (((size_t)jg * 128 + wv * 16 + kt2) * 64 + lane) * 8);
          } else {
            int j = jg * 16 + lrow;
            const float* pp = Wp + (size_t)j * Cz + kb + kt2 * 32 + lq * 8;
            #pragma unroll
            for (int ii = 0; ii < 8; ++ii) bfr[ii] = (short)f2bf(pp[ii]);
          }
          pc0 = __builtin_amdgcn_mfma_f32_16x16x32_bf16(af0[i], bfr, pc0, 0, 0, 0);
          pc1 = __builtin_amdgcn_mfma_f32_16x16x32_bf16(af1[i], bfr, pc1, 0, 0, 0);
        }
      }
      #pragma unroll
      for (int r = 0; r < 4; ++r) {
        pld[(((wv * 2 + 0) * 16) + lq * 4 + r) * 16 + lrow] = pc0[r];
        pld[(((wv * 2 + 1) * 16) + lq * 4 + r) * 16 + lrow] = pc1[r];
      }
      __syncthreads();
      if (tid < 256) {  // reduce 8 wave-partials; thread owns (b_p, jf2, jf2+1)
        float s0 = 0.f, s1 = 0.f;
        #pragma unroll
        for (int k8 = 0; k8 < 8; ++k8) {
          s0 += pld[(((k8 * 2 + mt_p) * 16) + row_p) * 16 + (jf2 & 15)];
          s1 += pld[(((k8 * 2 + mt_p) * 16) + row_p) * 16 + (jf2 & 15) + 1];
        }
        s0 = fminf(fmaxf(s0, -3.f), 3.f);
        s1 = fminf(fmaxf(s1, -3.f), 3.f);
        bool act = t < lenp;
        float hn0 = act ? s0 : h_old[0];
        float hn1 = act ? s1 : h_old[1];
        h_old[0] = hn0; h_old[1] = hn1;
        u32 hp = (u32)f2bf(hn0) | ((u32)f2bf(hn1) << 16);
        __hip_atomic_store((u32*)Hwr + (((size_t)b_p * Hz + jf2) >> 1), hp,
                           __ATOMIC_RELAXED, __HIP_MEMORY_SCOPE_AGENT);
        floatx2 ov = {act ? s0 : 0.f, act ? s1 : 0.f};
        __builtin_nontemporal_store(ov, (floatx2*)(outp + ((size_t)b_p * Tz + t) * Hz + jf2));
        if (t == Tz - 1) {
          __builtin_nontemporal_store(hn0, final_h + (size_t)b_p * Hz + jf2);
          __builtin_nontemporal_store(hn1, final_h + (size_t)b_p * Hz + jf2 + 1);
        }
      }
      __syncthreads();          // drain h stores (all waves)
      if (tid == 0) {
        __asm__ volatile("s_waitcnt vmcnt(0)" ::: "memory");
        __hip_atomic_store(&hfl[p * 16], t + 1, __ATOMIC_RELAXED, __HIP_MEMORY_SCOPE_AGENT);
      }
    }
  }
}

// ---------------- launcher ----------------

extern "C" void kernel_launch(void* const* d_in, const int* in_sizes, int n_in,
                              void* d_out, int out_size, void* d_ws, size_t ws_size,
                              hipStream_t stream) {
  const float* x   = (const float*)d_in[0];
  const int* lens  = (const int*)d_in[1];
  const float* Wi  = (const float*)d_in[2];
  const float* Wst = (const float*)d_in[3];
  const float* bst = (const float*)d_in[4];
  const float* Wp  = (const float*)d_in[5];

  float* outp    = (float*)d_out;
  float* final_h = outp + (size_t)Bz * Tz * Hz;
  float* final_c = final_h + (size_t)Bz * Hz;

  char* ws = (char*)d_ws;
  constexpr size_t OFF_H    = 0;                                    // 2x64 KB h bf16
  constexpr size_t OFF_AFL  = OFF_H + 2 * (size_t)Bz * Hz * 2;      // 131072 (+16 KB)
  constexpr size_t OFF_HFL  = OFF_AFL + 256 * 64;                   // 147456 (+4 KB)
  constexpr size_t ZERO_END = OFF_HFL + 64 * 64;                    // 151552
  constexpr size_t OFF_AB   = ZERO_END;                             // 2x512 KB abuf
  constexpr size_t OFF_WPK  = OFF_AB + 2 * (size_t)Bz * Cz * 2;     // 32 MB
  constexpr size_t OFF_WPP  = OFF_WPK + (size_t)16384 * 1024 * 2;   // 4 MB
  constexpr size_t OFF_XB   = OFF_WPP + (size_t)Cz * Hz * 2;        // 32 MB
  constexpr size_t NEED     = OFF_XB + (size_t)Bz * Tz * Iz * 2;    // ~69.2 MB

  unsigned short* Hbuf = (unsigned short*)(ws + OFF_H);
  int* afl      = (int*)(ws + OFF_AFL);
  int* hfl      = (int*)(ws + OFF_HFL);
  unsigned short* abuf = (unsigned short*)(ws + OFF_AB);
  short* wpk    = (short*)(ws + OFF_WPK);
  short* wpp    = (short*)(ws + OFF_WPP);
  unsigned short* xb = (unsigned short*)(ws + OFF_XB);

  const bool packed = (ws_size >= NEED);

  hipMemsetAsync(ws, 0, ZERO_END, stream);   // h0 + all flags

  if (packed) {
    precast_wpk<<<8192, 256, 0, stream>>>(Wi, Wst, wpk);
    precast_wpp<<<1024, 256, 0, stream>>>(Wp, wpp);
    precast_x<<<16384, 256, 0, stream>>>(x, xb);
  }

  if (packed) {
    lstm_persist<true><<<NWG, 512, 0, stream>>>(x, xb, Wi, Wst, Wp, wpk, wpp, bst, lens,
                                                Hbuf, afl, hfl, abuf,
                                                outp, final_h, final_c);
  } else {
    lstm_persist<false><<<NWG, 512, 0, stream>>>(x, nullptr, Wi, Wst, Wp, nullptr, nullptr,
                                                 bst, lens, Hbuf, afl, hfl, abuf,
                                                 outp, final_h, final_c);
  }
}